// Round 5
// baseline (168.044 us; speedup 1.0000x reference)
//
#include <hip/hip_runtime.h>
#include <stdint.h>

#define MAX_TRIALS 50
#define MARGIN 1.0f
#define BLOCK 256
#define SEG 1024  // elements per count/scatter segment; nseg <= 1024 (B <= 1M ok)

// ---------------- JAX threefry2x32, key = jax.random.key(42) = [0, 42] -----
// Verified bit-exact in rounds 1/3/4 (absmax 0.0). Do not touch.
__device__ __forceinline__ uint32_t rotl32(uint32_t x, uint32_t d) {
  return (x << d) | (x >> (32u - d));
}

__device__ __forceinline__ uint32_t threefry_0_42(uint32_t x0, uint32_t x1, int which) {
  const uint32_t k0 = 0u, k1 = 42u;
  const uint32_t k2 = k0 ^ k1 ^ 0x1BD11BDAu;
  const uint32_t ks[3] = {k0, k1, k2};
  const uint32_t rotA[4] = {13u, 15u, 26u, 6u};
  const uint32_t rotB[4] = {17u, 29u, 16u, 24u};
  x0 += ks[0];
  x1 += ks[1];
#pragma unroll
  for (int r = 0; r < 5; ++r) {
#pragma unroll
    for (int j = 0; j < 4; ++j) {
      uint32_t rot = (r & 1) ? rotB[j] : rotA[j];
      x0 += x1;
      x1 = rotl32(x1, rot);
      x1 ^= x0;
    }
    x0 += ks[(r + 1) % 3];
    x1 += ks[(r + 2) % 3] + (uint32_t)(r + 1);
  }
  return which ? x1 : x0;
}

// jax uniform element j of an (n,) draw, n = B*MAX_TRIALS:
// j < n/2 -> output 0 of threefry(j, j+n/2); else output 1 of (j-n/2, j)
__device__ __forceinline__ float sample_u(uint32_t j, uint32_t half) {
  uint32_t x0, x1;
  int which;
  if (j < half) { x0 = j; x1 = j + half; which = 0; }
  else          { x0 = j - half; x1 = j; which = 1; }
  uint32_t bits = threefry_0_42(x0, x1, which);
  return __uint_as_float((bits >> 9) | 0x3f800000u) - 1.0f;
}

// ---------------- K1: per-segment count (int4 loads) + zero arrival ctrs ---
__global__ void __launch_bounds__(BLOCK) count_kernel(const int* __restrict__ labels,
                                                      int* __restrict__ segCounts,
                                                      int* __restrict__ g1,
                                                      int* __restrict__ g2, int B) {
  const int t = threadIdx.x;
  const int seg = blockIdx.x;
  int e0 = seg * SEG + 4 * t;
  int c = 0;
  if (e0 + 3 < B) {
    int4 L = *reinterpret_cast<const int4*>(labels + e0);
    c = (L.x == 0) + (L.y == 0) + (L.z == 0) + (L.w == 0);
  } else {
    for (int k = 0; k < 4; ++k) {
      int e = e0 + k;
      if (e < B && labels[e] == 0) ++c;
    }
  }
#pragma unroll
  for (int off = 32; off > 0; off >>= 1) c += __shfl_down(c, off, 64);
  __shared__ int wc[4];
  int lane = t & 63, wave = t >> 6;
  if (lane == 0) wc[wave] = c;
  __syncthreads();
  if (t == 0) segCounts[seg] = wc[0] + wc[1] + wc[2] + wc[3];
  // zero the main kernel's arrival counters (ws is re-poisoned every call)
  if (seg == 0) {
    if (t < 64) g1[t * 16] = 0;  // 64 counters padded to one cache line each
    if (t == 64) g2[0] = 0;
  }
}

// ---------------- K2: fused scan + stable compaction of negative SCORES ----
// Every block re-derives its segment's global prefix from segCounts (L2-hot,
// 4KB) -- replaces the separate scan kernel (~15us dispatch gap saved).
__global__ void __launch_bounds__(BLOCK) scatter_kernel(const float* __restrict__ scores,
                                                        const int* __restrict__ labels,
                                                        const int* __restrict__ segCounts,
                                                        int* __restrict__ counters,
                                                        float* __restrict__ negScores,
                                                        int B, int nseg) {
  __shared__ int s_counts[1024];
  __shared__ int s_scan[BLOCK];
  const int t = threadIdx.x;
  const int seg = blockIdx.x;

  // load all segment counts (nseg <= 1024)
  int i0 = 4 * t;
  int4 c4 = {0, 0, 0, 0};
  if (i0 + 3 < nseg) {
    c4 = *reinterpret_cast<const int4*>(segCounts + i0);
  } else {
    if (i0 < nseg) c4.x = segCounts[i0];
    if (i0 + 1 < nseg) c4.y = segCounts[i0 + 1];
    if (i0 + 2 < nseg) c4.z = segCounts[i0 + 2];
    if (i0 + 3 < nseg) c4.w = segCounts[i0 + 3];
  }
  s_counts[i0] = c4.x;
  s_counts[i0 + 1] = c4.y;
  s_counts[i0 + 2] = c4.z;
  s_counts[i0 + 3] = c4.w;
  s_scan[t] = c4.x + c4.y + c4.z + c4.w;
  __syncthreads();
  // Hillis-Steele inclusive scan over 256 group sums (groups of 4 counts)
  for (int d = 1; d < BLOCK; d <<= 1) {
    int v = (t >= d) ? s_scan[t - d] : 0;
    __syncthreads();
    s_scan[t] += v;
    __syncthreads();
  }
  int q = seg >> 2, rem = seg & 3;
  int base = q ? s_scan[q - 1] : 0;
  if (rem > 0) base += s_counts[4 * q];
  if (rem > 1) base += s_counts[4 * q + 1];
  if (rem > 2) base += s_counts[4 * q + 2];
  if (seg == 0 && t == 0) counters[0] = s_scan[BLOCK - 1];  // num_neg
  __syncthreads();  // done reading s_scan/s_counts before reuse

  // my 4 consecutive elements (stable order: thread rank * 4 + k)
  int e0 = seg * SEG + 4 * t;
  int lab[4] = {1, 1, 1, 1};  // 1 == not negative
  float sc[4] = {0.f, 0.f, 0.f, 0.f};
  if (e0 + 3 < B) {
    int4 L = *reinterpret_cast<const int4*>(labels + e0);
    float4 S = *reinterpret_cast<const float4*>(scores + e0);
    lab[0] = L.x; lab[1] = L.y; lab[2] = L.z; lab[3] = L.w;
    sc[0] = S.x; sc[1] = S.y; sc[2] = S.z; sc[3] = S.w;
  } else {
    for (int k = 0; k < 4; ++k) {
      int e = e0 + k;
      if (e < B) { lab[k] = labels[e]; sc[k] = scores[e]; }
    }
  }
  int c = (lab[0] == 0) + (lab[1] == 0) + (lab[2] == 0) + (lab[3] == 0);
  s_scan[t] = c;
  __syncthreads();
  for (int d = 1; d < BLOCK; d <<= 1) {
    int v = (t >= d) ? s_scan[t - d] : 0;
    __syncthreads();
    s_scan[t] += v;
    __syncthreads();
  }
  int pos = base + s_scan[t] - c;  // exclusive prefix within segment + seg base
  for (int k = 0; k < 4; ++k)
    if (lab[k] == 0) negScores[pos++] = sc[k];
}

// ---------------- K3: two-phase sampling + fused tree-arrival finalize -----
// Phase A: 2 speculative independent trials per positive. Survivors -> LDS
// queue. Phase B: one wave per survivor, trials 2..49 lane-parallel.
// Finalize: partial[b] plain store; two-level arrival (64 padded group ctrs
// -> 1 super ctr; ~64 same-address atomics per line = ~1us, NOT the 53us a
// flat 4096-arrival counter would serialize to). Last block reduces partials
// with device-scope atomic reads.
__global__ void __launch_bounds__(BLOCK) warp_main(const float* __restrict__ scores,
                                                   const int* __restrict__ labels,
                                                   const float* __restrict__ negScores,
                                                   const int* __restrict__ counters,
                                                   float* __restrict__ partial,
                                                   int* __restrict__ g1,
                                                   int* __restrict__ g2,
                                                   float* __restrict__ out, int B) {
  __shared__ float H[MAX_TRIALS + 1];
  __shared__ int s_qe[BLOCK];
  __shared__ float s_qs[BLOCK];
  __shared__ int s_qn;
  __shared__ int s_final;
  __shared__ float s_bsum[4];

  const int tid = threadIdx.x;
  const int lane = tid & 63;
  const int wave = tid >> 6;

  if (tid == 0) {
    float a = 0.0f;  // fp32 sequential cumsum == jnp.cumsum of 1/k
    for (int k = 1; k <= MAX_TRIALS; ++k) { a += 1.0f / (float)k; H[k] = a; }
    s_qn = 0;
    s_final = 0;
  }
  __syncthreads();

  const int num_neg = counters[0];
  const float fneg = (float)num_neg;
  const uint32_t half = (uint32_t)(((unsigned long long)B * MAX_TRIALS) >> 1);
  const int e = blockIdx.x * BLOCK + tid;

  float acc = 0.0f;
  bool survive = false;
  float s = 0.0f;

  if (e < B && num_neg > 0 && labels[e] == 1) {
    s = scores[e];
    uint32_t jb = (uint32_t)e * (uint32_t)MAX_TRIALS;
    // both trials computed & gathered speculatively -> one memory latency
    float u0 = sample_u(jb, half);
    float u1 = sample_u(jb + 1u, half);
    int i0 = (int)(u0 * fneg);  // trunc toward zero == astype(int32)
    int i1 = (int)(u1 * fneg);
    if (i0 > num_neg - 1) i0 = num_neg - 1;
    if (i1 > num_neg - 1) i1 = num_neg - 1;
    float n0 = negScores[i0];
    float n1 = negScores[i1];
    if (n0 + MARGIN > s) {         // trials=0 -> rank=50
      float h = MARGIN - (s - n0);
      if (h < 0.0f) h = 0.0f;
      acc = H[50] * h;
    } else if (n1 + MARGIN > s) {  // trials=1 -> rank=25
      float h = MARGIN - (s - n1);
      if (h < 0.0f) h = 0.0f;
      acc = H[25] * h;
    } else {
      survive = true;
    }
  }

  // enqueue survivors into block-local LDS queue (order irrelevant for sum)
  unsigned long long m = __ballot(survive);
  int c = __popcll(m);
  if (c) {
    int wbase = 0;
    if (lane == 0) wbase = atomicAdd(&s_qn, c);  // LDS atomic: block-local, cheap
    wbase = __shfl(wbase, 0, 64);
    if (survive) {
      int p = wbase + __popcll(m & ((1ULL << lane) - 1ULL));
      s_qe[p] = e;
      s_qs[p] = s;
    }
  }
  __syncthreads();

  // phase B: one wave per survivor, lanes = trials 2..49
  const int qn = s_qn;
  for (int q = wave; q < qn; q += 4) {
    float sq = s_qs[q];
    int eq = s_qe[q];
    int t = 2 + lane;
    bool viol = false;
    float neg = 0.0f;
    if (t < MAX_TRIALS) {
      float u = sample_u((uint32_t)eq * (uint32_t)MAX_TRIALS + (uint32_t)t, half);
      int idx = (int)(u * fneg);
      if (idx > num_neg - 1) idx = num_neg - 1;
      neg = negScores[idx];
      viol = (neg + MARGIN > sq);
    }
    unsigned long long vm = __ballot(viol);
    if (vm) {
      int f = __ffsll(vm) - 1;  // lowest lane == first violating trial
      if (lane == f) {
        int trials = 2 + f;
        int rank = MAX_TRIALS / (trials + 1);
        if (rank < 1) rank = 1;
        float h = MARGIN - (sq - neg);
        if (h < 0.0f) h = 0.0f;
        acc += H[rank] * h;
      }
    }
    // vm == 0 -> no violation in 50 trials -> contributes 0 (matches ref)
  }

  // block reduce -> one plain store per block (distinct addresses)
  float v = acc;
#pragma unroll
  for (int off = 32; off > 0; off >>= 1) v += __shfl_down(v, off, 64);
  if (lane == 0) s_bsum[wave] = v;
  __syncthreads();

  if (tid == 0) {
    partial[blockIdx.x] = s_bsum[0] + s_bsum[1] + s_bsum[2] + s_bsum[3];
    __threadfence();  // release my partial before arriving
    int g = blockIdx.x & 63;
    int gsize = ((int)gridDim.x - 1 - g) / 64 + 1;  // blocks in my mod-64 group
    int old = atomicAdd(&g1[g * 16], 1);
    if (old == gsize - 1) {  // last of my group
      __threadfence();
      int ngroups = ((int)gridDim.x < 64) ? (int)gridDim.x : 64;
      int old2 = atomicAdd(g2, 1);
      if (old2 == ngroups - 1) s_final = 1;  // I am the last block overall
    }
  }
  __syncthreads();

  if (s_final) {
    // device-scope atomic reads guarantee coherent view of all partials
    float fv = 0.0f;
    for (int i = tid; i < (int)gridDim.x; i += BLOCK) fv += atomicAdd(&partial[i], 0.0f);
#pragma unroll
    for (int off = 32; off > 0; off >>= 1) fv += __shfl_down(fv, off, 64);
    if (lane == 0) s_bsum[wave] = fv;
    __syncthreads();
    if (tid == 0) {
      int np = B - num_neg;
      float tt = s_bsum[0] + s_bsum[1] + s_bsum[2] + s_bsum[3];
      float r = 0.0f;
      if (np > 0 && num_neg > 0) r = tt / (float)np;
      out[0] = r;
    }
  }
}

extern "C" void kernel_launch(void* const* d_in, const int* in_sizes, int n_in,
                              void* d_out, int out_size, void* d_ws, size_t ws_size,
                              hipStream_t stream) {
  const float* scores = (const float*)d_in[0];
  const int* labels = (const int*)d_in[1];
  int B = in_sizes[0];
  int nseg = (B + SEG - 1) / SEG;          // 1024 for B=1M (design limit: <=1024)
  int nb3 = (B + BLOCK - 1) / BLOCK;       // 4096

  // workspace layout (~4.25 MB)
  char* ws = (char*)d_ws;
  int* counters = (int*)ws;                 // [0]=num_neg
  int* g1 = (int*)(ws + 64);                // 64 arrival ctrs, 64B-padded (4KB)
  int* g2 = (int*)(ws + 64 + 4096);         // super arrival counter
  int* segCounts = (int*)(ws + 64 + 4096 + 64);          // nseg ints
  float* partial = (float*)(ws + 64 + 4096 + 64 + 4096); // nb3 floats
  float* negScores = (float*)(ws + 64 + 4096 + 64 + 4096 + 16384);  // B floats

  count_kernel<<<nseg, BLOCK, 0, stream>>>(labels, segCounts, g1, g2, B);
  scatter_kernel<<<nseg, BLOCK, 0, stream>>>(scores, labels, segCounts, counters,
                                             negScores, B, nseg);
  warp_main<<<nb3, BLOCK, 0, stream>>>(scores, labels, negScores, counters, partial,
                                       g1, g2, (float*)d_out, B);
}

// Round 6
// 94.037 us; speedup vs baseline: 1.7870x; 1.7870x over previous
//
#include <hip/hip_runtime.h>
#include <stdint.h>

#define MAX_TRIALS 50
#define MARGIN 1.0f
#define BLOCK 256
#define SEG 1024            // elements per count/scatter segment; nseg <= 1024
#define ME 8                // elements per thread in warp_main
#define MCHUNK (BLOCK * ME) // 2048 elements per warp_main block

// ---------------- JAX threefry2x32, key = jax.random.key(42) = [0, 42] -----
// Verified bit-exact in rounds 1/3/4/5 (absmax 0.0). Do not touch.
__device__ __forceinline__ uint32_t rotl32(uint32_t x, uint32_t d) {
  return (x << d) | (x >> (32u - d));
}

__device__ __forceinline__ uint32_t threefry_0_42(uint32_t x0, uint32_t x1, int which) {
  const uint32_t k0 = 0u, k1 = 42u;
  const uint32_t k2 = k0 ^ k1 ^ 0x1BD11BDAu;
  const uint32_t ks[3] = {k0, k1, k2};
  const uint32_t rotA[4] = {13u, 15u, 26u, 6u};
  const uint32_t rotB[4] = {17u, 29u, 16u, 24u};
  x0 += ks[0];
  x1 += ks[1];
#pragma unroll
  for (int r = 0; r < 5; ++r) {
#pragma unroll
    for (int j = 0; j < 4; ++j) {
      uint32_t rot = (r & 1) ? rotB[j] : rotA[j];
      x0 += x1;
      x1 = rotl32(x1, rot);
      x1 ^= x0;
    }
    x0 += ks[(r + 1) % 3];
    x1 += ks[(r + 2) % 3] + (uint32_t)(r + 1);
  }
  return which ? x1 : x0;
}

// jax uniform element j of an (n,) draw, n = B*MAX_TRIALS:
// j < n/2 -> output 0 of threefry(j, j+n/2); else output 1 of (j-n/2, j)
__device__ __forceinline__ float sample_u(uint32_t j, uint32_t half) {
  uint32_t x0, x1;
  int which;
  if (j < half) { x0 = j; x1 = j + half; which = 0; }
  else          { x0 = j - half; x1 = j; which = 1; }
  uint32_t bits = threefry_0_42(x0, x1, which);
  return __uint_as_float((bits >> 9) | 0x3f800000u) - 1.0f;
}

// ---------------- K1: per-segment count (int4 loads); zeroes out[0] --------
__global__ void __launch_bounds__(BLOCK) count_kernel(const int* __restrict__ labels,
                                                      int* __restrict__ segCounts,
                                                      float* __restrict__ out, int B) {
  const int t = threadIdx.x;
  const int seg = blockIdx.x;
  int e0 = seg * SEG + 4 * t;
  int c = 0;
  if (e0 + 3 < B) {
    int4 L = *reinterpret_cast<const int4*>(labels + e0);
    c = (L.x == 0) + (L.y == 0) + (L.z == 0) + (L.w == 0);
  } else {
    for (int k = 0; k < 4; ++k) {
      int e = e0 + k;
      if (e < B && labels[e] == 0) ++c;
    }
  }
#pragma unroll
  for (int off = 32; off > 0; off >>= 1) c += __shfl_down(c, off, 64);
  __shared__ int wc[4];
  int lane = t & 63, wave = t >> 6;
  if (lane == 0) wc[wave] = c;
  __syncthreads();
  if (t == 0) segCounts[seg] = wc[0] + wc[1] + wc[2] + wc[3];
  // d_out is re-poisoned to 0xAA each call; warp_main accumulates into it.
  if (seg == 0 && t == 0) out[0] = 0.0f;
}

// ---------------- K2: fused scan + stable compaction of negative SCORES ----
// Verified absmax 0.0 in round 5. Every block re-derives its segment's global
// prefix from segCounts (L2/L3-hot, 4KB).
__global__ void __launch_bounds__(BLOCK) scatter_kernel(const float* __restrict__ scores,
                                                        const int* __restrict__ labels,
                                                        const int* __restrict__ segCounts,
                                                        int* __restrict__ counters,
                                                        float* __restrict__ negScores,
                                                        int B, int nseg) {
  __shared__ int s_counts[1024];
  __shared__ int s_scan[BLOCK];
  const int t = threadIdx.x;
  const int seg = blockIdx.x;

  int i0 = 4 * t;
  int4 c4 = {0, 0, 0, 0};
  if (i0 + 3 < nseg) {
    c4 = *reinterpret_cast<const int4*>(segCounts + i0);
  } else {
    if (i0 < nseg) c4.x = segCounts[i0];
    if (i0 + 1 < nseg) c4.y = segCounts[i0 + 1];
    if (i0 + 2 < nseg) c4.z = segCounts[i0 + 2];
    if (i0 + 3 < nseg) c4.w = segCounts[i0 + 3];
  }
  s_counts[i0] = c4.x;
  s_counts[i0 + 1] = c4.y;
  s_counts[i0 + 2] = c4.z;
  s_counts[i0 + 3] = c4.w;
  s_scan[t] = c4.x + c4.y + c4.z + c4.w;
  __syncthreads();
  for (int d = 1; d < BLOCK; d <<= 1) {
    int v = (t >= d) ? s_scan[t - d] : 0;
    __syncthreads();
    s_scan[t] += v;
    __syncthreads();
  }
  int q = seg >> 2, rem = seg & 3;
  int base = q ? s_scan[q - 1] : 0;
  if (rem > 0) base += s_counts[4 * q];
  if (rem > 1) base += s_counts[4 * q + 1];
  if (rem > 2) base += s_counts[4 * q + 2];
  if (seg == 0 && t == 0) counters[0] = s_scan[BLOCK - 1];  // num_neg
  __syncthreads();  // done reading s_scan/s_counts before reuse

  int e0 = seg * SEG + 4 * t;
  int lab[4] = {1, 1, 1, 1};
  float sc[4] = {0.f, 0.f, 0.f, 0.f};
  if (e0 + 3 < B) {
    int4 L = *reinterpret_cast<const int4*>(labels + e0);
    float4 S = *reinterpret_cast<const float4*>(scores + e0);
    lab[0] = L.x; lab[1] = L.y; lab[2] = L.z; lab[3] = L.w;
    sc[0] = S.x; sc[1] = S.y; sc[2] = S.z; sc[3] = S.w;
  } else {
    for (int k = 0; k < 4; ++k) {
      int e = e0 + k;
      if (e < B) { lab[k] = labels[e]; sc[k] = scores[e]; }
    }
  }
  int c = (lab[0] == 0) + (lab[1] == 0) + (lab[2] == 0) + (lab[3] == 0);
  s_scan[t] = c;
  __syncthreads();
  for (int d = 1; d < BLOCK; d <<= 1) {
    int v = (t >= d) ? s_scan[t - d] : 0;
    __syncthreads();
    s_scan[t] += v;
    __syncthreads();
  }
  int pos = base + s_scan[t] - c;  // segment base + exclusive intra-segment prefix
  for (int k = 0; k < 4; ++k)
    if (lab[k] == 0) negScores[pos++] = sc[k];
}

// ---------------- K3: two-phase sampling, 8 elem/thread, fence-free tail ---
// Phase A: per element, 2 speculative trials; gathers batched 8-deep per
// 4-element group (issue all, then resolve). Survivors -> LDS queue.
// Phase B: one wave per survivor, trials 2..49 lane-parallel, ballot+ffs.
// Tail: ONE fence-free atomicAdd(out, block_sum/num_pos) per block -- 512
// same-address atomics ~11us, overlapped with straggler blocks. Round-5
// lesson: NO __threadfence / arrival counters in the wide kernel (+70us).
__global__ void __launch_bounds__(BLOCK) warp_main(const float* __restrict__ scores,
                                                   const int* __restrict__ labels,
                                                   const float* __restrict__ negScores,
                                                   const int* __restrict__ counters,
                                                   float* __restrict__ out, int B) {
  __shared__ float H[MAX_TRIALS + 1];
  __shared__ int s_qe[MCHUNK];
  __shared__ float s_qs[MCHUNK];
  __shared__ int s_qn;
  __shared__ float s_bsum[4];

  const int tid = threadIdx.x;
  const int lane = tid & 63;
  const int wave = tid >> 6;

  if (tid == 0) {
    float a = 0.0f;  // fp32 sequential cumsum == jnp.cumsum of 1/k
    for (int k = 1; k <= MAX_TRIALS; ++k) { a += 1.0f / (float)k; H[k] = a; }
    s_qn = 0;
  }
  __syncthreads();

  const int num_neg = counters[0];
  if (num_neg == 0) return;  // uniform: out[0] already 0 from K1 (ref: valid=false)

  const float fneg = (float)num_neg;
  const uint32_t half = (uint32_t)(((unsigned long long)B * MAX_TRIALS) >> 1);
  const int chunk0 = blockIdx.x * MCHUNK;

  float acc = 0.0f;
  int my_e[ME];
  float my_s[ME];
  int nsurv = 0;

#pragma unroll
  for (int g = 0; g < ME / 4; ++g) {
    int e0 = chunk0 + g * (BLOCK * 4) + 4 * tid;  // lane-consecutive 16B: coalesced
    int lab[4] = {1, 1, 1, 1};
    float sc[4] = {0.f, 0.f, 0.f, 0.f};
    if (e0 + 3 < B) {
      int4 L = *reinterpret_cast<const int4*>(labels + e0);
      float4 S = *reinterpret_cast<const float4*>(scores + e0);
      lab[0] = L.x; lab[1] = L.y; lab[2] = L.z; lab[3] = L.w;
      sc[0] = S.x; sc[1] = S.y; sc[2] = S.z; sc[3] = S.w;
    } else {
      for (int k = 0; k < 4; ++k) {
        int e = e0 + k;
        if (e < B) { lab[k] = labels[e]; sc[k] = scores[e]; }
      }
    }
    // issue all 8 gathers for this group before resolving (MLP)
    float n0[4], n1[4];
#pragma unroll
    for (int k = 0; k < 4; ++k) {
      if (lab[k] == 1) {
        uint32_t jb = (uint32_t)(e0 + k) * (uint32_t)MAX_TRIALS;
        float u0 = sample_u(jb, half);
        float u1 = sample_u(jb + 1u, half);
        int i0 = (int)(u0 * fneg);  // trunc toward zero == astype(int32)
        int i1 = (int)(u1 * fneg);
        if (i0 > num_neg - 1) i0 = num_neg - 1;
        if (i1 > num_neg - 1) i1 = num_neg - 1;
        n0[k] = negScores[i0];
        n1[k] = negScores[i1];
      }
    }
#pragma unroll
    for (int k = 0; k < 4; ++k) {
      if (lab[k] == 1) {
        float s = sc[k];
        if (n0[k] + MARGIN > s) {         // trials=0 -> rank=50
          float h = MARGIN - (s - n0[k]);
          if (h < 0.0f) h = 0.0f;
          acc += H[50] * h;
        } else if (n1[k] + MARGIN > s) {  // trials=1 -> rank=25
          float h = MARGIN - (s - n1[k]);
          if (h < 0.0f) h = 0.0f;
          acc += H[25] * h;
        } else {
          my_e[nsurv] = e0 + k;
          my_s[nsurv] = s;
          ++nsurv;
        }
      }
    }
  }

  // enqueue survivors (order irrelevant for the sum); LDS atomic is cheap
  int qp = 0;
  if (nsurv) qp = atomicAdd(&s_qn, nsurv);
  for (int i = 0; i < nsurv; ++i) {
    s_qe[qp + i] = my_e[i];
    s_qs[qp + i] = my_s[i];
  }
  __syncthreads();

  // phase B: one wave per survivor, lanes = trials 2..49
  const int qn = s_qn;
  for (int q = wave; q < qn; q += 4) {
    float sq = s_qs[q];
    int eq = s_qe[q];
    int t = 2 + lane;
    bool viol = false;
    float neg = 0.0f;
    if (t < MAX_TRIALS) {
      float u = sample_u((uint32_t)eq * (uint32_t)MAX_TRIALS + (uint32_t)t, half);
      int idx = (int)(u * fneg);
      if (idx > num_neg - 1) idx = num_neg - 1;
      neg = negScores[idx];
      viol = (neg + MARGIN > sq);
    }
    unsigned long long vm = __ballot(viol);
    if (vm) {
      int f = __ffsll(vm) - 1;  // lowest lane == first violating trial
      if (lane == f) {
        int trials = 2 + f;
        int rank = MAX_TRIALS / (trials + 1);
        if (rank < 1) rank = 1;
        float h = MARGIN - (sq - neg);
        if (h < 0.0f) h = 0.0f;
        acc += H[rank] * h;
      }
    }
    // vm == 0 -> no violation in 50 trials -> contributes 0 (matches ref)
  }

  // block reduce -> one fence-free atomic per block (pre-scaled by 1/num_pos)
  float v = acc;
#pragma unroll
  for (int off = 32; off > 0; off >>= 1) v += __shfl_down(v, off, 64);
  if (lane == 0) s_bsum[wave] = v;
  __syncthreads();
  if (tid == 0) {
    int np = B - num_neg;
    if (np > 0) {
      float bs = s_bsum[0] + s_bsum[1] + s_bsum[2] + s_bsum[3];
      atomicAdd(out, bs * (1.0f / (float)np));
    }
  }
}

extern "C" void kernel_launch(void* const* d_in, const int* in_sizes, int n_in,
                              void* d_out, int out_size, void* d_ws, size_t ws_size,
                              hipStream_t stream) {
  const float* scores = (const float*)d_in[0];
  const int* labels = (const int*)d_in[1];
  int B = in_sizes[0];
  int nseg = (B + SEG - 1) / SEG;        // 1024 for B=1M (design limit: <=1024)
  int nb3 = (B + MCHUNK - 1) / MCHUNK;   // 512

  // workspace layout (~4.2 MB)
  char* ws = (char*)d_ws;
  int* counters = (int*)ws;                     // [0]=num_neg
  int* segCounts = (int*)(ws + 64);             // nseg ints
  float* negScores = (float*)(ws + 64 + 4096);  // B floats (first num_neg used)

  count_kernel<<<nseg, BLOCK, 0, stream>>>(labels, segCounts, (float*)d_out, B);
  scatter_kernel<<<nseg, BLOCK, 0, stream>>>(scores, labels, segCounts, counters,
                                             negScores, B, nseg);
  warp_main<<<nb3, BLOCK, 0, stream>>>(scores, labels, negScores, counters,
                                       (float*)d_out, B);
}

// Round 7
// 89.533 us; speedup vs baseline: 1.8769x; 1.0503x over previous
//
#include <hip/hip_runtime.h>
#include <stdint.h>

#define MAX_TRIALS 50
#define MARGIN 1.0f

// K1: fused count+scan+scatter (decoupled lookback)
#define SBLOCK 256
#define SEG 1024                 // elements per segment (4/thread, int4)
// K2: sampler
#define MBLOCK 1024              // 16 waves/block; 512 blocks -> 32 waves/CU
#define MME 2
#define MCHUNK (MBLOCK * MME)    // 2048 elements per block

#define FLAG_AGG 1ULL
#define FLAG_INC 2ULL

// ---------------- JAX threefry2x32, key = jax.random.key(42) = [0, 42] -----
// Verified bit-exact rounds 1/3/4/5/6 (absmax 0.0). Do not touch.
__device__ __forceinline__ uint32_t rotl32(uint32_t x, uint32_t d) {
  return (x << d) | (x >> (32u - d));
}

__device__ __forceinline__ uint32_t threefry_0_42(uint32_t x0, uint32_t x1, int which) {
  const uint32_t k0 = 0u, k1 = 42u;
  const uint32_t k2 = k0 ^ k1 ^ 0x1BD11BDAu;
  const uint32_t ks[3] = {k0, k1, k2};
  const uint32_t rotA[4] = {13u, 15u, 26u, 6u};
  const uint32_t rotB[4] = {17u, 29u, 16u, 24u};
  x0 += ks[0];
  x1 += ks[1];
#pragma unroll
  for (int r = 0; r < 5; ++r) {
#pragma unroll
    for (int j = 0; j < 4; ++j) {
      uint32_t rot = (r & 1) ? rotB[j] : rotA[j];
      x0 += x1;
      x1 = rotl32(x1, rot);
      x1 ^= x0;
    }
    x0 += ks[(r + 1) % 3];
    x1 += ks[(r + 2) % 3] + (uint32_t)(r + 1);
  }
  return which ? x1 : x0;
}

__device__ __forceinline__ float sample_u(uint32_t j, uint32_t half) {
  uint32_t x0, x1;
  int which;
  if (j < half) { x0 = j; x1 = j + half; which = 0; }
  else          { x0 = j - half; x1 = j; which = 1; }
  uint32_t bits = threefry_0_42(x0, x1, which);
  return __uint_as_float((bits >> 9) | 0x3f800000u) - 1.0f;
}

// ---------------- K1: fused count + decoupled-lookback scan + scatter ------
// desc[seg] = (flag<<32)|count: flag/value packed in ONE atomic word, so no
// fences needed (r5 lesson: per-block __threadfence machinery cost +60us).
// ws poison 0xAA..AA has hi-word 0xAAAAAAAA != 1/2 -> reads as "not ready".
// Grid (1024 blocks x 256 thr) <= co-resident capacity (8/CU x 256) -> all
// blocks resident -> lookback spin cannot deadlock.
__global__ void __launch_bounds__(SBLOCK) scan_scatter_kernel(
    const float* __restrict__ scores, const int* __restrict__ labels,
    unsigned long long* __restrict__ desc, int* __restrict__ counters,
    float* __restrict__ negScores, float* __restrict__ out, int B, int nseg) {
  __shared__ int s_scan[SBLOCK];
  __shared__ int s_base;
  const int t = threadIdx.x;
  const int seg = blockIdx.x;

  if (seg == 0 && t == 0) out[0] = 0.0f;  // d_out poisoned each call; K2 accumulates

  // load my 4 consecutive elements (stable order: thread rank * 4 + k)
  int e0 = seg * SEG + 4 * t;
  int lab[4] = {1, 1, 1, 1};
  float sc[4] = {0.f, 0.f, 0.f, 0.f};
  if (e0 + 3 < B) {
    int4 L = *reinterpret_cast<const int4*>(labels + e0);
    float4 S = *reinterpret_cast<const float4*>(scores + e0);
    lab[0] = L.x; lab[1] = L.y; lab[2] = L.z; lab[3] = L.w;
    sc[0] = S.x; sc[1] = S.y; sc[2] = S.z; sc[3] = S.w;
  } else {
    for (int k = 0; k < 4; ++k) {
      int e = e0 + k;
      if (e < B) { lab[k] = labels[e]; sc[k] = scores[e]; }
    }
  }
  int c = (lab[0] == 0) + (lab[1] == 0) + (lab[2] == 0) + (lab[3] == 0);
  s_scan[t] = c;
  __syncthreads();
  for (int d = 1; d < SBLOCK; d <<= 1) {  // Hillis-Steele inclusive
    int v = (t >= d) ? s_scan[t - d] : 0;
    __syncthreads();
    s_scan[t] += v;
    __syncthreads();
  }
  const int cnt = s_scan[SBLOCK - 1];  // my segment's negative count

  if (seg == 0) {
    if (t == 0) {
      atomicExch(&desc[0], (FLAG_INC << 32) | (unsigned)cnt);
      s_base = 0;
      if (nseg == 1) counters[0] = cnt;
    }
  } else {
    if (t == 0) atomicExch(&desc[seg], (FLAG_AGG << 32) | (unsigned)cnt);
    if (t < 64) {  // wave 0: lane-parallel lookback, 64 predecessors/window
      int running = 0;  // maintained in lane 0
      int w = 0;
      bool done = false;
      while (!done) {
        int idx = seg - 1 - w * 64 - t;
        unsigned flag;
        int val;
        do {
          if (idx >= 0) {
            unsigned long long v = atomicAdd(&desc[idx], 0ULL);  // coherent read
            flag = (unsigned)(v >> 32);
            val = (int)(unsigned)v;
          } else {
            flag = (unsigned)FLAG_INC;  // virtual inclusive 0 below seg 0
            val = 0;
          }
        } while (!__all(flag == 1u || flag == 2u));
        unsigned long long incmask = __ballot(flag == 2u);
        int contrib;
        if (incmask) {
          int l = __ffsll(incmask) - 1;      // nearest inclusive entry
          contrib = (t <= l) ? val : 0;      // lanes < l are aggregates
          done = true;
        } else {
          contrib = val;                     // all aggregates; keep walking
          ++w;
        }
#pragma unroll
        for (int off = 32; off > 0; off >>= 1) contrib += __shfl_down(contrib, off, 64);
        if (t == 0) running += contrib;
      }
      if (t == 0) {
        atomicExch(&desc[seg], (FLAG_INC << 32) | (unsigned)(running + cnt));
        s_base = running;
        if (seg == nseg - 1) counters[0] = running + cnt;  // num_neg
      }
    }
  }
  __syncthreads();
  const int base = s_base;

  int pos = base + s_scan[t] - c;  // segment base + exclusive intra-segment prefix
  for (int k = 0; k < 4; ++k)
    if (lab[k] == 0) negScores[pos++] = sc[k];
}

// ---------------- K2: two-phase sampling, 1024 thr x 2 elem, 512 blocks ----
// 512 blocks x 16 waves = 2/CU = 32 waves/CU (r6's 512x4 gave only 8 -> the
// 47us latency wall). Tail: ONE fence-free atomicAdd per block (512 total,
// r6-proven). Phase A: 2 speculative trials/element, 4 gathers in flight.
// Phase B: one wave per survivor, trials 2..49 lane-parallel, ballot+ffs.
__global__ void __launch_bounds__(MBLOCK, 8) warp_main(
    const float* __restrict__ scores, const int* __restrict__ labels,
    const float* __restrict__ negScores, const int* __restrict__ counters,
    float* __restrict__ out, int B) {
  __shared__ float H[MAX_TRIALS + 1];
  __shared__ int s_qe[MCHUNK];
  __shared__ float s_qs[MCHUNK];
  __shared__ int s_qn;
  __shared__ float s_bsum[MBLOCK / 64];

  const int tid = threadIdx.x;
  const int lane = tid & 63;
  const int wave = tid >> 6;

  if (tid == 0) {
    float a = 0.0f;  // fp32 sequential cumsum == jnp.cumsum of 1/k
    for (int k = 1; k <= MAX_TRIALS; ++k) { a += 1.0f / (float)k; H[k] = a; }
    s_qn = 0;
  }
  __syncthreads();

  const int num_neg = counters[0];
  if (num_neg == 0) return;  // uniform exit after sync; out[0] already 0 from K1

  const float fneg = (float)num_neg;
  const uint32_t half = (uint32_t)(((unsigned long long)B * MAX_TRIALS) >> 1);

  float acc = 0.0f;
  int my_e[MME];
  float my_s[MME];
  int nsurv = 0;

  int e0 = blockIdx.x * MCHUNK + 2 * tid;  // lane-consecutive 8B: coalesced
  int lab[2] = {1, 1};
  float sc[2] = {0.f, 0.f};
  if (e0 + 1 < B) {
    int2 L = *reinterpret_cast<const int2*>(labels + e0);
    float2 S = *reinterpret_cast<const float2*>(scores + e0);
    lab[0] = L.x; lab[1] = L.y;
    sc[0] = S.x; sc[1] = S.y;
  } else {
    for (int k = 0; k < 2; ++k) {
      int e = e0 + k;
      if (e < B) { lab[k] = labels[e]; sc[k] = scores[e]; }
    }
  }
  // issue all 4 gathers before resolving (MLP)
  float n0[2], n1[2];
#pragma unroll
  for (int k = 0; k < 2; ++k) {
    if (lab[k] == 1) {
      uint32_t jb = (uint32_t)(e0 + k) * (uint32_t)MAX_TRIALS;
      float u0 = sample_u(jb, half);
      float u1 = sample_u(jb + 1u, half);
      int i0 = (int)(u0 * fneg);  // trunc toward zero == astype(int32)
      int i1 = (int)(u1 * fneg);
      if (i0 > num_neg - 1) i0 = num_neg - 1;
      if (i1 > num_neg - 1) i1 = num_neg - 1;
      n0[k] = negScores[i0];
      n1[k] = negScores[i1];
    }
  }
#pragma unroll
  for (int k = 0; k < 2; ++k) {
    if (lab[k] == 1) {
      float s = sc[k];
      if (n0[k] + MARGIN > s) {         // trials=0 -> rank=50
        float h = MARGIN - (s - n0[k]);
        if (h < 0.0f) h = 0.0f;
        acc += H[50] * h;
      } else if (n1[k] + MARGIN > s) {  // trials=1 -> rank=25
        float h = MARGIN - (s - n1[k]);
        if (h < 0.0f) h = 0.0f;
        acc += H[25] * h;
      } else {
        my_e[nsurv] = e0 + k;
        my_s[nsurv] = s;
        ++nsurv;
      }
    }
  }

  // enqueue survivors (order irrelevant for the sum); LDS atomic is cheap
  int qp = 0;
  if (nsurv) qp = atomicAdd(&s_qn, nsurv);
  for (int i = 0; i < nsurv; ++i) {
    s_qe[qp + i] = my_e[i];
    s_qs[qp + i] = my_s[i];
  }
  __syncthreads();

  // phase B: one wave per survivor, lanes = trials 2..49
  const int qn = s_qn;
  for (int q = wave; q < qn; q += MBLOCK / 64) {
    float sq = s_qs[q];
    int eq = s_qe[q];
    int t = 2 + lane;
    bool viol = false;
    float neg = 0.0f;
    if (t < MAX_TRIALS) {
      float u = sample_u((uint32_t)eq * (uint32_t)MAX_TRIALS + (uint32_t)t, half);
      int idx = (int)(u * fneg);
      if (idx > num_neg - 1) idx = num_neg - 1;
      neg = negScores[idx];
      viol = (neg + MARGIN > sq);
    }
    unsigned long long vm = __ballot(viol);
    if (vm) {
      int f = __ffsll(vm) - 1;  // lowest lane == first violating trial
      if (lane == f) {
        int trials = 2 + f;
        int rank = MAX_TRIALS / (trials + 1);
        if (rank < 1) rank = 1;
        float h = MARGIN - (sq - neg);
        if (h < 0.0f) h = 0.0f;
        acc += H[rank] * h;
      }
    }
    // vm == 0 -> no violation in 50 trials -> contributes 0 (matches ref)
  }

  // block reduce -> one fence-free atomic per block (pre-scaled by 1/num_pos)
  float v = acc;
#pragma unroll
  for (int off = 32; off > 0; off >>= 1) v += __shfl_down(v, off, 64);
  if (lane == 0) s_bsum[wave] = v;
  __syncthreads();
  if (tid == 0) {
    int np = B - num_neg;
    if (np > 0) {
      float bs = 0.0f;
      for (int i = 0; i < MBLOCK / 64; ++i) bs += s_bsum[i];
      atomicAdd(out, bs * (1.0f / (float)np));
    }
  }
}

extern "C" void kernel_launch(void* const* d_in, const int* in_sizes, int n_in,
                              void* d_out, int out_size, void* d_ws, size_t ws_size,
                              hipStream_t stream) {
  const float* scores = (const float*)d_in[0];
  const int* labels = (const int*)d_in[1];
  int B = in_sizes[0];
  int nseg = (B + SEG - 1) / SEG;         // 1024 for B=1M
  int nb2 = (B + MCHUNK - 1) / MCHUNK;    // 512

  // workspace layout (~4.2 MB)
  char* ws = (char*)d_ws;
  int* counters = (int*)ws;                                  // [0]=num_neg
  unsigned long long* desc = (unsigned long long*)(ws + 64); // nseg packed descriptors
  float* negScores = (float*)(ws + 64 + 8 * 1024);           // B floats

  scan_scatter_kernel<<<nseg, SBLOCK, 0, stream>>>(scores, labels, desc, counters,
                                                   negScores, (float*)d_out, B, nseg);
  warp_main<<<nb2, MBLOCK, 0, stream>>>(scores, labels, negScores, counters,
                                        (float*)d_out, B);
}